// Round 1
// baseline (1473.492 us; speedup 1.0000x reference)
//
#include <hip/hip_runtime.h>
#include <hip/hip_bf16.h>

// WeightOnlyInt4Linear: C[M,N] = x[M,K] @ W^T, W[o,k] = (q[o,k]-8)*scale[g,o]+zero[g,o]
// M=8192, N=4096, K=4096, group=128 along K.
// Fused dequant -> bf16 MFMA GEMM. 128x128 tile, BK=64, 4 waves (2x2), XOR-swizzled LDS.

#define M_ROWS 8192
#define N_OUT  4096
#define K_IN   4096
#define BM 128
#define BN 128
#define BK 64
#define NTILES_N (N_OUT / BN)  // 32

typedef __attribute__((ext_vector_type(8))) short bf16x8;
typedef __attribute__((ext_vector_type(4))) float f32x4;

__device__ __forceinline__ unsigned short f2bf(float f) {
    union { float f; unsigned u; } c; c.f = f;
    unsigned r = (c.u + 0x7FFFu + ((c.u >> 16) & 1u)) >> 16;  // RNE
    return (unsigned short)r;
}

// XOR swizzle: row-major [row][64 bf16] tile, 128B row stride.
// byte offset within row XOR'd with (row&7)<<4 -> ds_read_b128 of a 16-row
// column slice spreads over 8 distinct 16B slots (2-way = free, m136).
__device__ __forceinline__ int swz(int row, int byte_off) {
    return row * 128 + (byte_off ^ ((row & 7) << 4));
}

__global__ __launch_bounds__(256) void int4_gemm(
    const float* __restrict__ x,
    const int*   __restrict__ wq,
    const float* __restrict__ sz,
    float*       __restrict__ out)
{
    __shared__ short A_lds[BM * BK];
    __shared__ short B_lds[BN * BK];
    char* Ab = (char*)A_lds;
    char* Bb = (char*)B_lds;

    const int bid = blockIdx.x;
    const int mt = bid / NTILES_N;
    const int nt = bid % NTILES_N;
    const int m0 = mt * BM;
    const int o0 = nt * BN;

    const int t    = threadIdx.x;
    const int lane = t & 63;
    const int wid  = t >> 6;
    const int wr   = wid >> 1;   // wave row (0..1) -> 64-row half
    const int wc   = wid & 1;    // wave col (0..1) -> 64-col half

    // staging decomposition: 256 threads, each loads 4 elems (16B global for A/B)
    const int sr = t >> 4;        // 0..15 row within 16-row chunk
    const int sc = (t & 15) * 4;  // element col 0..60

    f32x4 acc[4][4];
    #pragma unroll
    for (int i = 0; i < 4; ++i)
        #pragma unroll
        for (int j = 0; j < 4; ++j)
            acc[i][j] = (f32x4){0.f, 0.f, 0.f, 0.f};

    const int frag_r = lane & 15;        // A row / B col / D col within 16-block
    const int kb     = (lane >> 4) * 8;  // k base within 32 for A/B operands

    for (int kt = 0; kt < K_IN / BK; ++kt) {
        const int k0 = kt * BK;
        const int g  = k0 >> 7;  // uniform group per tile (BK=64 divides 128)

        // ---- stage A: x fp32 -> bf16, swizzled LDS ----
        #pragma unroll
        for (int it = 0; it < 8; ++it) {
            const int row = it * 16 + sr;
            const float4 v = *(const float4*)(x + (size_t)(m0 + row) * K_IN + k0 + sc);
            ushort4 h;
            h.x = f2bf(v.x); h.y = f2bf(v.y); h.z = f2bf(v.z); h.w = f2bf(v.w);
            *(ushort4*)(Ab + swz(row, sc * 2)) = h;
        }
        // ---- stage B: int4-in-int32 -> dequant -> bf16, swizzled LDS ----
        #pragma unroll
        for (int it = 0; it < 8; ++it) {
            const int row = it * 16 + sr;  // output-feature row within tile
            const int4 q = *(const int4*)(wq + (size_t)(o0 + row) * K_IN + k0 + sc);
            const float2 s2 = *(const float2*)(sz + ((size_t)g * N_OUT + o0 + row) * 2);
            ushort4 h;
            h.x = f2bf((float)(q.x - 8) * s2.x + s2.y);
            h.y = f2bf((float)(q.y - 8) * s2.x + s2.y);
            h.z = f2bf((float)(q.z - 8) * s2.x + s2.y);
            h.w = f2bf((float)(q.w - 8) * s2.x + s2.y);
            *(ushort4*)(Bb + swz(row, sc * 2)) = h;
        }
        __syncthreads();

        // ---- MFMA: 2 k-steps of 32, 4x4 fragments per wave ----
        #pragma unroll
        for (int kk = 0; kk < BK; kk += 32) {
            bf16x8 a[4], b[4];
            #pragma unroll
            for (int i = 0; i < 4; ++i) {
                const int row = wr * 64 + i * 16 + frag_r;
                a[i] = *(const bf16x8*)(Ab + swz(row, (kk + kb) * 2));
            }
            #pragma unroll
            for (int j = 0; j < 4; ++j) {
                const int row = wc * 64 + j * 16 + frag_r;
                b[j] = *(const bf16x8*)(Bb + swz(row, (kk + kb) * 2));
            }
            #pragma unroll
            for (int i = 0; i < 4; ++i)
                #pragma unroll
                for (int j = 0; j < 4; ++j)
                    acc[i][j] = __builtin_amdgcn_mfma_f32_16x16x32_bf16(a[i], b[j], acc[i][j], 0, 0, 0);
        }
        __syncthreads();
    }

    // ---- epilogue: D col=lane&15, row=(lane>>4)*4+r (m89-verified) ----
    const int crow = (lane >> 4) * 4;
    #pragma unroll
    for (int i = 0; i < 4; ++i) {
        #pragma unroll
        for (int j = 0; j < 4; ++j) {
            #pragma unroll
            for (int r = 0; r < 4; ++r) {
                const int gr = m0 + wr * 64 + i * 16 + crow + r;
                const int gc = o0 + wc * 64 + j * 16 + frag_r;
                out[(size_t)gr * N_OUT + gc] = acc[i][j][r];
            }
        }
    }
}

extern "C" void kernel_launch(void* const* d_in, const int* in_sizes, int n_in,
                              void* d_out, int out_size, void* d_ws, size_t ws_size,
                              hipStream_t stream) {
    const float* x  = (const float*)d_in[0];
    const int*   wq = (const int*)d_in[1];
    const float* sz = (const float*)d_in[2];
    float* out = (float*)d_out;

    dim3 grid((M_ROWS / BM) * (N_OUT / BN));  // 64*32 = 2048
    dim3 block(256);
    hipLaunchKernelGGL(int4_gemm, grid, block, 0, stream, x, wq, sz, out);
}

// Round 2
// 439.291 us; speedup vs baseline: 3.3543x; 3.3543x over previous
//
#include <hip/hip_runtime.h>
#include <hip/hip_bf16.h>
#include <stdint.h>

// WeightOnlyInt4Linear: C[M,N] = x[M,K] @ W^T, W[o,k] = (q[o,k]-8)*scale[g,o]+zero[g,o]
// Two-step: (1) convert x->bf16, dequant W->bf16 into d_ws (memory-bound prepass),
// (2) m97-structure bf16 GEMM: 128x128 tile, BK=64, 4 waves, global_load_lds w=16,
// linear LDS, 2-barrier loop, XCD-swizzled grid. Fallback: fused kernel if ws too small.

#define M_ROWS 8192
#define N_OUT  4096
#define K_IN   4096
#define BM 128
#define BN 128
#define BK 64
#define NTILES_N (N_OUT / BN)              // 32
#define NWG ((M_ROWS / BM) * (N_OUT / BN)) // 2048

typedef __attribute__((ext_vector_type(8))) short bf16x8;
typedef __attribute__((ext_vector_type(4))) float f32x4;

__device__ __forceinline__ unsigned short f2bf(float f) {
    union { float f; unsigned u; } c; c.f = f;
    unsigned r = (c.u + 0x7FFFu + ((c.u >> 16) & 1u)) >> 16;  // RNE
    return (unsigned short)r;
}

__device__ __forceinline__ void gload_lds16(const void* g, void* l) {
    __builtin_amdgcn_global_load_lds(
        (const __attribute__((address_space(1))) void*)g,
        (__attribute__((address_space(3))) void*)l, 16, 0, 0);
}

// ---------------- prepass 1: x fp32 -> bf16 ----------------
__global__ __launch_bounds__(256) void conv_x(const float* __restrict__ x,
                                              unsigned short* __restrict__ xb) {
    const int stride = gridDim.x * blockDim.x;
    const int nchunk = M_ROWS * K_IN / 4;
    for (int c = blockIdx.x * blockDim.x + threadIdx.x; c < nchunk; c += stride) {
        const float4 v = ((const float4*)x)[c];
        ushort4 h;
        h.x = f2bf(v.x); h.y = f2bf(v.y); h.z = f2bf(v.z); h.w = f2bf(v.w);
        ((ushort4*)xb)[c] = h;
    }
}

// ---------------- prepass 2: int4-in-int32 -> dequant bf16 ----------------
__global__ __launch_bounds__(256) void conv_w(const int* __restrict__ wq,
                                              const float* __restrict__ sz,
                                              unsigned short* __restrict__ wb) {
    const int stride = gridDim.x * blockDim.x;
    const int nchunk = N_OUT * K_IN / 4;
    for (int c = blockIdx.x * blockDim.x + threadIdx.x; c < nchunk; c += stride) {
        const int4 q = ((const int4*)wq)[c];
        const int o  = c >> 10;            // K/4 = 1024 chunks per out-row
        const int kc = (c & 1023) * 4;
        const int g  = kc >> 7;
        const float2 s2 = *(const float2*)(sz + ((size_t)g * N_OUT + o) * 2);
        ushort4 h;
        h.x = f2bf((float)(q.x - 8) * s2.x + s2.y);
        h.y = f2bf((float)(q.y - 8) * s2.x + s2.y);
        h.z = f2bf((float)(q.z - 8) * s2.x + s2.y);
        h.w = f2bf((float)(q.w - 8) * s2.x + s2.y);
        ((ushort4*)wb)[c] = h;
    }
}

// ---------------- main GEMM: m97 structure ----------------
// A = xb [M,K] bf16 row-major; B = wb [N,K] bf16 row-major (i.e. B^T); C fp32 [M,N].
__global__ __launch_bounds__(256) void gemm_bf16(const unsigned short* __restrict__ A,
                                                 const unsigned short* __restrict__ B,
                                                 float* __restrict__ out) {
    __shared__ __align__(1024) short A_lds[BM * BK];  // 16 KB, linear [row][64]
    __shared__ __align__(1024) short B_lds[BN * BK];  // 16 KB

    // bijective XCD swizzle (NWG % 8 == 0): XCD x owns a contiguous chunk of tiles
    const int bid = blockIdx.x;
    const int swb = (bid & 7) * (NWG / 8) + (bid >> 3);
    const int mt = swb / NTILES_N;
    const int nt = swb % NTILES_N;
    const int m0 = mt * BM;
    const int o0 = nt * BN;

    const int t    = threadIdx.x;
    const int lane = t & 63;
    const int wid  = t >> 6;
    const int wr   = wid >> 1;
    const int wc   = wid & 1;

    f32x4 acc[4][4];
    #pragma unroll
    for (int i = 0; i < 4; ++i)
        #pragma unroll
        for (int j = 0; j < 4; ++j)
            acc[i][j] = (f32x4){0.f, 0.f, 0.f, 0.f};

    const int frag_r = lane & 15;
    const int kb     = (lane >> 4) * 8;

    // per-lane staging geometry: chunk c (1024B = 8 rows of 128B), lane covers 16B
    const int srow = lane >> 3;        // 0..7 within chunk
    const int scol = (lane & 7) * 8;   // element col, 8 bf16 = 16B

    for (int kt = 0; kt < K_IN / BK; ++kt) {
        const int k0 = kt * BK;
        #pragma unroll
        for (int it = 0; it < 4; ++it) {
            const int c = wid * 4 + it;            // wave-uniform chunk id
            const int row = c * 8 + srow;
            gload_lds16(A + (size_t)(m0 + row) * K_IN + k0 + scol, (char*)A_lds + c * 1024);
            gload_lds16(B + (size_t)(o0 + row) * K_IN + k0 + scol, (char*)B_lds + c * 1024);
        }
        __syncthreads();  // compiler drains vmcnt(0) before s_barrier

        #pragma unroll
        for (int kk = 0; kk < BK; kk += 32) {
            bf16x8 a[4], b[4];
            #pragma unroll
            for (int i = 0; i < 4; ++i) {
                const int row = wr * 64 + i * 16 + frag_r;
                a[i] = *(const bf16x8*)((char*)A_lds + row * 128 + (kk + kb) * 2);
            }
            #pragma unroll
            for (int j = 0; j < 4; ++j) {
                const int row = wc * 64 + j * 16 + frag_r;
                b[j] = *(const bf16x8*)((char*)B_lds + row * 128 + (kk + kb) * 2);
            }
            #pragma unroll
            for (int i = 0; i < 4; ++i)
                #pragma unroll
                for (int j = 0; j < 4; ++j)
                    acc[i][j] = __builtin_amdgcn_mfma_f32_16x16x32_bf16(a[i], b[j], acc[i][j], 0, 0, 0);
        }
        __syncthreads();
    }

    const int crow = (lane >> 4) * 4;
    #pragma unroll
    for (int i = 0; i < 4; ++i)
        #pragma unroll
        for (int j = 0; j < 4; ++j)
            #pragma unroll
            for (int r = 0; r < 4; ++r) {
                const int gr = m0 + wr * 64 + i * 16 + crow + r;
                const int gc = o0 + wc * 64 + j * 16 + frag_r;
                out[(size_t)gr * N_OUT + gc] = acc[i][j][r];
            }
}

// ---------------- fallback: fused dequant GEMM (round-1 kernel) ----------------
__device__ __forceinline__ int swz(int row, int byte_off) {
    return row * 128 + (byte_off ^ ((row & 7) << 4));
}

__global__ __launch_bounds__(256) void int4_gemm_fused(
    const float* __restrict__ x,
    const int*   __restrict__ wq,
    const float* __restrict__ sz,
    float*       __restrict__ out)
{
    __shared__ short A_lds[BM * BK];
    __shared__ short B_lds[BN * BK];
    char* Ab = (char*)A_lds;
    char* Bb = (char*)B_lds;

    const int bid = blockIdx.x;
    const int mt = bid / NTILES_N;
    const int nt = bid % NTILES_N;
    const int m0 = mt * BM;
    const int o0 = nt * BN;

    const int t    = threadIdx.x;
    const int lane = t & 63;
    const int wid  = t >> 6;
    const int wr   = wid >> 1;
    const int wc   = wid & 1;

    const int sr = t >> 4;
    const int sc = (t & 15) * 4;

    f32x4 acc[4][4];
    #pragma unroll
    for (int i = 0; i < 4; ++i)
        #pragma unroll
        for (int j = 0; j < 4; ++j)
            acc[i][j] = (f32x4){0.f, 0.f, 0.f, 0.f};

    const int frag_r = lane & 15;
    const int kb     = (lane >> 4) * 8;

    for (int kt = 0; kt < K_IN / BK; ++kt) {
        const int k0 = kt * BK;
        const int g  = k0 >> 7;
        #pragma unroll
        for (int it = 0; it < 8; ++it) {
            const int row = it * 16 + sr;
            const float4 v = *(const float4*)(x + (size_t)(m0 + row) * K_IN + k0 + sc);
            ushort4 h;
            h.x = f2bf(v.x); h.y = f2bf(v.y); h.z = f2bf(v.z); h.w = f2bf(v.w);
            *(ushort4*)(Ab + swz(row, sc * 2)) = h;
        }
        #pragma unroll
        for (int it = 0; it < 8; ++it) {
            const int row = it * 16 + sr;
            const int4 q = *(const int4*)(wq + (size_t)(o0 + row) * K_IN + k0 + sc);
            const float2 s2 = *(const float2*)(sz + ((size_t)g * N_OUT + o0 + row) * 2);
            ushort4 h;
            h.x = f2bf((float)(q.x - 8) * s2.x + s2.y);
            h.y = f2bf((float)(q.y - 8) * s2.x + s2.y);
            h.z = f2bf((float)(q.z - 8) * s2.x + s2.y);
            h.w = f2bf((float)(q.w - 8) * s2.x + s2.y);
            *(ushort4*)(Bb + swz(row, sc * 2)) = h;
        }
        __syncthreads();

        #pragma unroll
        for (int kk = 0; kk < BK; kk += 32) {
            bf16x8 a[4], b[4];
            #pragma unroll
            for (int i = 0; i < 4; ++i)
                a[i] = *(const bf16x8*)(Ab + swz(wr * 64 + i * 16 + frag_r, (kk + kb) * 2));
            #pragma unroll
            for (int j = 0; j < 4; ++j)
                b[j] = *(const bf16x8*)(Bb + swz(wc * 64 + j * 16 + frag_r, (kk + kb) * 2));
            #pragma unroll
            for (int i = 0; i < 4; ++i)
                #pragma unroll
                for (int j = 0; j < 4; ++j)
                    acc[i][j] = __builtin_amdgcn_mfma_f32_16x16x32_bf16(a[i], b[j], acc[i][j], 0, 0, 0);
        }
        __syncthreads();
    }

    const int crow = (lane >> 4) * 4;
    #pragma unroll
    for (int i = 0; i < 4; ++i)
        #pragma unroll
        for (int j = 0; j < 4; ++j)
            #pragma unroll
            for (int r = 0; r < 4; ++r) {
                const int gr = m0 + wr * 64 + i * 16 + crow + r;
                const int gc = o0 + wc * 64 + j * 16 + frag_r;
                out[(size_t)gr * N_OUT + gc] = acc[i][j][r];
            }
}

extern "C" void kernel_launch(void* const* d_in, const int* in_sizes, int n_in,
                              void* d_out, int out_size, void* d_ws, size_t ws_size,
                              hipStream_t stream) {
    const float* x  = (const float*)d_in[0];
    const int*   wq = (const int*)d_in[1];
    const float* sz = (const float*)d_in[2];
    float* out = (float*)d_out;

    const size_t need = ((size_t)M_ROWS * K_IN + (size_t)N_OUT * K_IN) * sizeof(unsigned short);
    if (ws_size >= need) {
        unsigned short* xb = (unsigned short*)d_ws;
        unsigned short* wb = xb + (size_t)M_ROWS * K_IN;
        hipLaunchKernelGGL(conv_x, dim3(2048), dim3(256), 0, stream, x, xb);
        hipLaunchKernelGGL(conv_w, dim3(2048), dim3(256), 0, stream, wq, sz, wb);
        hipLaunchKernelGGL(gemm_bf16, dim3(NWG), dim3(256), 0, stream, xb, wb, out);
    } else {
        hipLaunchKernelGGL(int4_gemm_fused, dim3(NWG), dim3(256), 0, stream, x, wq, sz, out);
    }
}

// Round 3
// 303.215 us; speedup vs baseline: 4.8596x; 1.4488x over previous
//
#include <hip/hip_runtime.h>
#include <hip/hip_bf16.h>
#include <stdint.h>

// WeightOnlyInt4Linear: C[M,N] = x[M,K] @ W^T, W = dequant int4 (group=128 on K).
// Step 1: memory-bound prepasses convert x->bf16 and W->bf16 into d_ws.
// Step 2: 256x256 8-phase bf16 GEMM (T2 swizzle + T3/T4 counted-vmcnt + T5 setprio).

#define M_ROWS 8192
#define N_OUT  4096
#define K_IN   4096
#define NT_K   64           // K tiles of BK=64
#define NWG    512          // (8192/256) * (4096/256) = 32*16

typedef __attribute__((ext_vector_type(8))) short bf16x8;
typedef __attribute__((ext_vector_type(4))) float f32x4;

__device__ __forceinline__ unsigned short f2bf(float f) {
    union { float f; unsigned u; } c; c.f = f;
    return (unsigned short)((c.u + 0x7FFFu + ((c.u >> 16) & 1u)) >> 16);  // RNE
}

__device__ __forceinline__ void gload_lds16(const void* g, void* l) {
    __builtin_amdgcn_global_load_lds(
        (const __attribute__((address_space(1))) void*)g,
        (__attribute__((address_space(3))) void*)l, 16, 0, 0);
}

// ---------------- prepass 1: x fp32 -> bf16 ----------------
__global__ __launch_bounds__(256) void conv_x(const float* __restrict__ x,
                                              unsigned short* __restrict__ xb) {
    const int stride = gridDim.x * blockDim.x;
    const int nchunk = M_ROWS * K_IN / 4;
    for (int c = blockIdx.x * blockDim.x + threadIdx.x; c < nchunk; c += stride) {
        const float4 v = ((const float4*)x)[c];
        ushort4 h;
        h.x = f2bf(v.x); h.y = f2bf(v.y); h.z = f2bf(v.z); h.w = f2bf(v.w);
        ((ushort4*)xb)[c] = h;
    }
}

// ---------------- prepass 2: int4-in-int32 -> dequant bf16 ----------------
__global__ __launch_bounds__(256) void conv_w(const int* __restrict__ wq,
                                              const float* __restrict__ sz,
                                              unsigned short* __restrict__ wb) {
    const int stride = gridDim.x * blockDim.x;
    const int nchunk = N_OUT * K_IN / 4;
    for (int c = blockIdx.x * blockDim.x + threadIdx.x; c < nchunk; c += stride) {
        const int4 q = ((const int4*)wq)[c];
        const int o  = c >> 10;
        const int kc = (c & 1023) * 4;
        const int g  = kc >> 7;
        const float2 s2 = *(const float2*)(sz + ((size_t)g * N_OUT + o) * 2);
        ushort4 h;
        h.x = f2bf((float)(q.x - 8) * s2.x + s2.y);
        h.y = f2bf((float)(q.y - 8) * s2.x + s2.y);
        h.z = f2bf((float)(q.z - 8) * s2.x + s2.y);
        h.w = f2bf((float)(q.w - 8) * s2.x + s2.y);
        ((ushort4*)wb)[c] = h;
    }
}

// ---------------- main GEMM: 256^2 8-phase ----------------
// A = xb [M,K] bf16 row-major; B = wb [N,K] bf16 row-major; C fp32 [M,N].
__global__ __launch_bounds__(512) void gemm_8ph(const unsigned short* __restrict__ A,
                                                const unsigned short* __restrict__ B,
                                                float* __restrict__ out) {
    __shared__ short Als[2 * 256 * 64];   // 64 KiB: 2 dbuf x [256 rows][64 bf16]
    __shared__ short Bls[2 * 256 * 64];   // 64 KiB

    const int bid = blockIdx.x;
    const int swb = (bid & 7) * (NWG / 8) + (bid >> 3);   // bijective XCD swizzle
    const int m0 = (swb >> 4) * 256;
    const int o0 = (swb & 15) * 256;

    const int t    = threadIdx.x;
    const int lane = t & 63;
    const int wid  = t >> 6;
    const int wm   = wid >> 2;   // 0..1 -> 128-row half of A
    const int wn   = wid & 3;    // 0..3 -> 64-row stripe of B

    // staging geometry: wave covers 2 x 1KiB chunks (8 rows x 128B each);
    // LDS dest is linear, global source col is pre-swizzled (same XOR involution as reads)
    const int srow = lane >> 3;                    // 0..7 row within chunk
    const int scol = ((lane & 7) ^ srow) * 8;      // pre-swizzled element col
    // fragment-read geometry
    const int fr   = lane & 15;
    const int rxm  = (fr & 7) << 4;                // XOR mask (row&7)<<4
    const int cb0  = (lane >> 4) * 16;             // col byte base within k-step

#define STAGE_A(BUF, H, ST) do { \
    const int k0_ = (ST) * 64; \
    _Pragma("unroll") \
    for (int l_ = 0; l_ < 2; ++l_) { \
        const int ch_ = wid * 2 + l_; \
        const int row_ = (H) * 128 + ch_ * 8 + srow; \
        gload_lds16(A + (size_t)(m0 + row_) * K_IN + k0_ + scol, \
                    (char*)Als + (BUF) * 32768 + (H) * 16384 + ch_ * 1024); \
    } } while (0)

#define STAGE_B(BUF, H, ST) do { \
    const int k0_ = (ST) * 64; \
    _Pragma("unroll") \
    for (int l_ = 0; l_ < 2; ++l_) { \
        const int ch_ = wid * 2 + l_; \
        const int row_ = (H) * 128 + ch_ * 8 + srow; \
        gload_lds16(B + (size_t)(o0 + row_) * K_IN + k0_ + scol, \
                    (char*)Bls + (BUF) * 32768 + (H) * 16384 + ch_ * 1024); \
    } } while (0)

#define LDA_F(BUF, M, KK) (*(const bf16x8*)((const char*)Als + (BUF) * 32768 + \
    (wm * 128 + (M) * 16 + fr) * 128 + ((((KK) * 64) + cb0) ^ rxm)))
#define LDB_F(BUF, N, KK) (*(const bf16x8*)((const char*)Bls + (BUF) * 32768 + \
    (wn * 64 + (N) * 16 + fr) * 128 + ((((KK) * 64) + cb0) ^ rxm)))

    f32x4 acc[8][4];
    #pragma unroll
    for (int m = 0; m < 8; ++m)
        #pragma unroll
        for (int n = 0; n < 4; ++n)
            acc[m][n] = (f32x4){0.f, 0.f, 0.f, 0.f};

    // prologue: tile0 {A0,A1,B0,B1} + tile1 {B0,B1}; wait tile0 (4 loads in flight)
    STAGE_A(0, 0, 0); STAGE_A(0, 1, 0); STAGE_B(0, 0, 0); STAGE_B(0, 1, 0);
    STAGE_B(1, 0, 1); STAGE_B(1, 1, 1);
    asm volatile("s_waitcnt vmcnt(4)" ::: "memory");
    __builtin_amdgcn_s_barrier();

    for (int kt = 0; kt < NT_K; kt += 2) {
        #pragma unroll
        for (int p = 0; p < 2; ++p) {
            const int cn  = p ^ 1;
            const int tn1 = (kt + p + 1) & (NT_K - 1);   // staging wraps at the end (writes
            const int tn2 = (kt + p + 2) & (NT_K - 1);   // are hazard-safe and never read)

            bf16x8 aLo[4][2], aHi[4][2], bLo[2][2], bHi[2][2];

            // ---- phase 1: read A-lo + B-lo (12 ds_reads), stage A0(t+1), MFMA Q00 ----
            #pragma unroll
            for (int m = 0; m < 4; ++m) { aLo[m][0] = LDA_F(p, m, 0); aLo[m][1] = LDA_F(p, m, 1); }
            #pragma unroll
            for (int n = 0; n < 2; ++n) { bLo[n][0] = LDB_F(p, n, 0); bLo[n][1] = LDB_F(p, n, 1); }
            STAGE_A(cn, 0, tn1);
            __builtin_amdgcn_s_barrier();
            asm volatile("s_waitcnt lgkmcnt(0)" ::: "memory");
            __builtin_amdgcn_sched_barrier(0);
            __builtin_amdgcn_s_setprio(1);
            #pragma unroll
            for (int m = 0; m < 4; ++m)
                #pragma unroll
                for (int n = 0; n < 2; ++n) {
                    acc[m][n] = __builtin_amdgcn_mfma_f32_16x16x32_bf16(aLo[m][0], bLo[n][0], acc[m][n], 0, 0, 0);
                    acc[m][n] = __builtin_amdgcn_mfma_f32_16x16x32_bf16(aLo[m][1], bLo[n][1], acc[m][n], 0, 0, 0);
                }
            __builtin_amdgcn_s_setprio(0);
            __builtin_amdgcn_sched_barrier(0);
            __builtin_amdgcn_s_barrier();

            // ---- phase 2: read B-hi (4 ds_reads), stage A1(t+1), MFMA Q01 ----
            #pragma unroll
            for (int n = 0; n < 2; ++n) { bHi[n][0] = LDB_F(p, n + 2, 0); bHi[n][1] = LDB_F(p, n + 2, 1); }
            STAGE_A(cn, 1, tn1);
            __builtin_amdgcn_s_barrier();
            asm volatile("s_waitcnt lgkmcnt(0)" ::: "memory");
            __builtin_amdgcn_sched_barrier(0);
            __builtin_amdgcn_s_setprio(1);
            #pragma unroll
            for (int m = 0; m < 4; ++m)
                #pragma unroll
                for (int n = 0; n < 2; ++n) {
                    acc[m][n + 2] = __builtin_amdgcn_mfma_f32_16x16x32_bf16(aLo[m][0], bHi[n][0], acc[m][n + 2], 0, 0, 0);
                    acc[m][n + 2] = __builtin_amdgcn_mfma_f32_16x16x32_bf16(aLo[m][1], bHi[n][1], acc[m][n + 2], 0, 0, 0);
                }
            __builtin_amdgcn_s_setprio(0);
            __builtin_amdgcn_sched_barrier(0);
            __builtin_amdgcn_s_barrier();

            // ---- phase 3: read A-hi (8 ds_reads), stage B0(t+2), MFMA Q11 ----
            #pragma unroll
            for (int m = 0; m < 4; ++m) { aHi[m][0] = LDA_F(p, m + 4, 0); aHi[m][1] = LDA_F(p, m + 4, 1); }
            STAGE_B(p, 0, tn2);
            __builtin_amdgcn_s_barrier();
            asm volatile("s_waitcnt lgkmcnt(0)" ::: "memory");
            __builtin_amdgcn_sched_barrier(0);
            __builtin_amdgcn_s_setprio(1);
            #pragma unroll
            for (int m = 0; m < 4; ++m)
                #pragma unroll
                for (int n = 0; n < 2; ++n) {
                    acc[m + 4][n + 2] = __builtin_amdgcn_mfma_f32_16x16x32_bf16(aHi[m][0], bHi[n][0], acc[m + 4][n + 2], 0, 0, 0);
                    acc[m + 4][n + 2] = __builtin_amdgcn_mfma_f32_16x16x32_bf16(aHi[m][1], bHi[n][1], acc[m + 4][n + 2], 0, 0, 0);
                }
            __builtin_amdgcn_s_setprio(0);
            __builtin_amdgcn_sched_barrier(0);
            __builtin_amdgcn_s_barrier();

            // ---- phase 4: stage B1(t+2), MFMA Q10, counted vmcnt(4) ----
            STAGE_B(p, 1, tn2);
            __builtin_amdgcn_s_barrier();
            __builtin_amdgcn_s_setprio(1);
            #pragma unroll
            for (int m = 0; m < 4; ++m)
                #pragma unroll
                for (int n = 0; n < 2; ++n) {
                    acc[m + 4][n] = __builtin_amdgcn_mfma_f32_16x16x32_bf16(aHi[m][0], bLo[n][0], acc[m + 4][n], 0, 0, 0);
                    acc[m + 4][n] = __builtin_amdgcn_mfma_f32_16x16x32_bf16(aHi[m][1], bLo[n][1], acc[m + 4][n], 0, 0, 0);
                }
            __builtin_amdgcn_s_setprio(0);
            __builtin_amdgcn_sched_barrier(0);
            asm volatile("s_waitcnt vmcnt(4)" ::: "memory");
            __builtin_amdgcn_s_barrier();
        }
    }

    asm volatile("s_waitcnt vmcnt(0)" ::: "memory");

    // epilogue: D col=lane&15, row=(lane>>4)*4+r
    const int crow = (lane >> 4) * 4;
    #pragma unroll
    for (int m = 0; m < 8; ++m)
        #pragma unroll
        for (int n = 0; n < 4; ++n)
            #pragma unroll
            for (int r = 0; r < 4; ++r)
                out[(size_t)(m0 + wm * 128 + m * 16 + crow + r) * N_OUT +
                    (o0 + wn * 64 + n * 16 + fr)] = acc[m][n][r];

#undef STAGE_A
#undef STAGE_B
#undef LDA_F
#undef LDB_F
}

// ---------------- fallback: fused dequant GEMM (round-1 kernel) ----------------
__device__ __forceinline__ int fswz(int row, int byte_off) {
    return row * 128 + (byte_off ^ ((row & 7) << 4));
}

__global__ __launch_bounds__(256) void int4_gemm_fused(
    const float* __restrict__ x,
    const int*   __restrict__ wq,
    const float* __restrict__ sz,
    float*       __restrict__ out)
{
    __shared__ short A_lds[128 * 64];
    __shared__ short B_lds[128 * 64];
    char* Ab = (char*)A_lds;
    char* Bb = (char*)B_lds;

    const int bid = blockIdx.x;
    const int mt = bid / 32;
    const int nt = bid % 32;
    const int m0 = mt * 128;
    const int o0 = nt * 128;

    const int t    = threadIdx.x;
    const int lane = t & 63;
    const int wid  = t >> 6;
    const int wr   = wid >> 1;
    const int wc   = wid & 1;
    const int sr = t >> 4;
    const int sc = (t & 15) * 4;

    f32x4 acc[4][4];
    #pragma unroll
    for (int i = 0; i < 4; ++i)
        #pragma unroll
        for (int j = 0; j < 4; ++j)
            acc[i][j] = (f32x4){0.f, 0.f, 0.f, 0.f};

    const int frag_r = lane & 15;
    const int kb     = (lane >> 4) * 8;

    for (int kt = 0; kt < K_IN / 64; ++kt) {
        const int k0 = kt * 64;
        const int g  = k0 >> 7;
        #pragma unroll
        for (int it = 0; it < 8; ++it) {
            const int row = it * 16 + sr;
            const float4 v = *(const float4*)(x + (size_t)(m0 + row) * K_IN + k0 + sc);
            ushort4 h;
            h.x = f2bf(v.x); h.y = f2bf(v.y); h.z = f2bf(v.z); h.w = f2bf(v.w);
            *(ushort4*)(Ab + fswz(row, sc * 2)) = h;
        }
        #pragma unroll
        for (int it = 0; it < 8; ++it) {
            const int row = it * 16 + sr;
            const int4 q = *(const int4*)(wq + (size_t)(o0 + row) * K_IN + k0 + sc);
            const float2 s2 = *(const float2*)(sz + ((size_t)g * N_OUT + o0 + row) * 2);
            ushort4 h;
            h.x = f2bf((float)(q.x - 8) * s2.x + s2.y);
            h.y = f2bf((float)(q.y - 8) * s2.x + s2.y);
            h.z = f2bf((float)(q.z - 8) * s2.x + s2.y);
            h.w = f2bf((float)(q.w - 8) * s2.x + s2.y);
            *(ushort4*)(Bb + fswz(row, sc * 2)) = h;
        }
        __syncthreads();

        #pragma unroll
        for (int kk = 0; kk < 64; kk += 32) {
            bf16x8 a[4], b[4];
            #pragma unroll
            for (int i = 0; i < 4; ++i)
                a[i] = *(const bf16x8*)(Ab + fswz(wr * 64 + i * 16 + frag_r, (kk + kb) * 2));
            #pragma unroll
            for (int j = 0; j < 4; ++j)
                b[j] = *(const bf16x8*)(Bb + fswz(wc * 64 + j * 16 + frag_r, (kk + kb) * 2));
            #pragma unroll
            for (int i = 0; i < 4; ++i)
                #pragma unroll
                for (int j = 0; j < 4; ++j)
                    acc[i][j] = __builtin_amdgcn_mfma_f32_16x16x32_bf16(a[i], b[j], acc[i][j], 0, 0, 0);
        }
        __syncthreads();
    }

    const int crow = (lane >> 4) * 4;
    #pragma unroll
    for (int i = 0; i < 4; ++i)
        #pragma unroll
        for (int j = 0; j < 4; ++j)
            #pragma unroll
            for (int r = 0; r < 4; ++r) {
                const int gr = m0 + wr * 64 + i * 16 + crow + r;
                const int gc = o0 + wc * 64 + j * 16 + frag_r;
                out[(size_t)gr * N_OUT + gc] = acc[i][j][r];
            }
}

extern "C" void kernel_launch(void* const* d_in, const int* in_sizes, int n_in,
                              void* d_out, int out_size, void* d_ws, size_t ws_size,
                              hipStream_t stream) {
    const float* x  = (const float*)d_in[0];
    const int*   wq = (const int*)d_in[1];
    const float* sz = (const float*)d_in[2];
    float* out = (float*)d_out;

    const size_t need = ((size_t)M_ROWS * K_IN + (size_t)N_OUT * K_IN) * sizeof(unsigned short);
    if (ws_size >= need) {
        unsigned short* xb = (unsigned short*)d_ws;
        unsigned short* wb = xb + (size_t)M_ROWS * K_IN;
        hipLaunchKernelGGL(conv_x, dim3(2048), dim3(256), 0, stream, x, xb);
        hipLaunchKernelGGL(conv_w, dim3(2048), dim3(256), 0, stream, wq, sz, wb);
        hipLaunchKernelGGL(gemm_8ph, dim3(NWG), dim3(512), 0, stream, xb, wb, out);
    } else {
        hipLaunchKernelGGL(int4_gemm_fused, dim3(2048), dim3(256), 0, stream, x, wq, sz, out);
    }
}

// Round 4
// 300.024 us; speedup vs baseline: 4.9113x; 1.0106x over previous
//
#include <hip/hip_runtime.h>
#include <hip/hip_bf16.h>
#include <stdint.h>

// WeightOnlyInt4Linear: C[M,N] = x[M,K] @ W^T, W = dequant int4 (group=128 on K).
// Step 1: fused memory-bound prepass converts x->bf16 and W->bf16 into d_ws.
// Step 2: 256x256 8-phase bf16 GEMM, kk-split counted lgkmcnt waits (hide LDS
//         reads under MFMA), T2 swizzle + counted-vmcnt + setprio.

#define M_ROWS 8192
#define N_OUT  4096
#define K_IN   4096
#define NT_K   64           // K tiles of BK=64
#define NWG    512          // (8192/256) * (4096/256) = 32*16

typedef __attribute__((ext_vector_type(8))) short bf16x8;
typedef __attribute__((ext_vector_type(4))) float f32x4;

__device__ __forceinline__ unsigned short f2bf(float f) {
    union { float f; unsigned u; } c; c.f = f;
    return (unsigned short)((c.u + 0x7FFFu + ((c.u >> 16) & 1u)) >> 16);  // RNE
}

__device__ __forceinline__ void gload_lds16(const void* g, void* l) {
    __builtin_amdgcn_global_load_lds(
        (const __attribute__((address_space(1))) void*)g,
        (__attribute__((address_space(3))) void*)l, 16, 0, 0);
}

// ---------------- fused prepass: x f32->bf16 AND wq int4->bf16 ----------------
#define NXCH (M_ROWS * K_IN / 4)   // 8388608 float4 chunks
#define NWCH (N_OUT * K_IN / 4)    // 4194304 int4 chunks
__global__ __launch_bounds__(256) void conv_all(const float* __restrict__ x,
                                                const int*   __restrict__ wq,
                                                const float* __restrict__ sz,
                                                unsigned short* __restrict__ xb,
                                                unsigned short* __restrict__ wb) {
    const int stride = gridDim.x * blockDim.x;
    for (int c = blockIdx.x * blockDim.x + threadIdx.x; c < NXCH + NWCH; c += stride) {
        if (c < NXCH) {
            const float4 v = ((const float4*)x)[c];
            ushort4 h;
            h.x = f2bf(v.x); h.y = f2bf(v.y); h.z = f2bf(v.z); h.w = f2bf(v.w);
            ((ushort4*)xb)[c] = h;
        } else {
            const int cw = c - NXCH;
            const int4 q = ((const int4*)wq)[cw];
            const int o  = cw >> 10;            // K/4 = 1024 chunks per out-row
            const int g  = (cw & 1023) >> 5;    // *4/128
            const float2 s2 = *(const float2*)(sz + ((size_t)g * N_OUT + o) * 2);
            ushort4 h;
            h.x = f2bf((float)(q.x - 8) * s2.x + s2.y);
            h.y = f2bf((float)(q.y - 8) * s2.x + s2.y);
            h.z = f2bf((float)(q.z - 8) * s2.x + s2.y);
            h.w = f2bf((float)(q.w - 8) * s2.x + s2.y);
            ((ushort4*)wb)[cw] = h;
        }
    }
}

// ---------------- main GEMM: 256^2 8-phase, kk-split waits ----------------
// A = xb [M,K] bf16 row-major; B = wb [N,K] bf16 row-major; C fp32 [M,N].
__global__ __launch_bounds__(512) void gemm_8ph(const unsigned short* __restrict__ A,
                                                const unsigned short* __restrict__ B,
                                                float* __restrict__ out) {
    __shared__ short Als[2 * 256 * 64];   // 64 KiB: 2 dbuf x [256 rows][64 bf16]
    __shared__ short Bls[2 * 256 * 64];   // 64 KiB

    const int bid = blockIdx.x;
    const int swb = (bid & 7) * (NWG / 8) + (bid >> 3);   // bijective XCD swizzle
    const int m0 = (swb >> 4) * 256;
    const int o0 = (swb & 15) * 256;

    const int t    = threadIdx.x;
    const int lane = t & 63;
    const int wid  = t >> 6;
    const int wm   = wid >> 2;   // 0..1 -> 128-row half of A
    const int wn   = wid & 3;    // 0..3 -> 64-row stripe of B

    // staging: LDS dest linear; global source col pre-swizzled (same XOR involution)
    const int srow = lane >> 3;                    // 0..7 row within 1KiB chunk
    const int scol = ((lane & 7) ^ srow) * 8;      // pre-swizzled element col
    // fragment-read geometry
    const int fr   = lane & 15;
    const int rxm  = (fr & 7) << 4;                // XOR mask (row&7)<<4
    const int cb0  = (lane >> 4) * 16;             // col byte base within k-step

#define STAGE_A(BUF, H, ST) do { \
    const int k0_ = (ST) * 64; \
    _Pragma("unroll") \
    for (int l_ = 0; l_ < 2; ++l_) { \
        const int ch_ = wid * 2 + l_; \
        const int row_ = (H) * 128 + ch_ * 8 + srow; \
        gload_lds16(A + (size_t)(m0 + row_) * K_IN + k0_ + scol, \
                    (char*)Als + (BUF) * 32768 + (H) * 16384 + ch_ * 1024); \
    } } while (0)

#define STAGE_B(BUF, H, ST) do { \
    const int k0_ = (ST) * 64; \
    _Pragma("unroll") \
    for (int l_ = 0; l_ < 2; ++l_) { \
        const int ch_ = wid * 2 + l_; \
        const int row_ = (H) * 128 + ch_ * 8 + srow; \
        gload_lds16(B + (size_t)(o0 + row_) * K_IN + k0_ + scol, \
                    (char*)Bls + (BUF) * 32768 + (H) * 16384 + ch_ * 1024); \
    } } while (0)

#define LDA_F(BUF, M, KK) (*(const bf16x8*)((const char*)Als + (BUF) * 32768 + \
    (wm * 128 + (M) * 16 + fr) * 128 + ((((KK) * 64) + cb0) ^ rxm)))
#define LDB_F(BUF, N, KK) (*(const bf16x8*)((const char*)Bls + (BUF) * 32768 + \
    (wn * 64 + (N) * 16 + fr) * 128 + ((((KK) * 64) + cb0) ^ rxm)))

#define SB0() __builtin_amdgcn_sched_barrier(0)

    f32x4 acc[8][4];
    #pragma unroll
    for (int m = 0; m < 8; ++m)
        #pragma unroll
        for (int n = 0; n < 4; ++n)
            acc[m][n] = (f32x4){0.f, 0.f, 0.f, 0.f};

    // prologue: tile0 {A0,A1,B0,B1} + tile1 {B0,B1}; wait tile0 (4 loads in flight)
    STAGE_A(0, 0, 0); STAGE_A(0, 1, 0); STAGE_B(0, 0, 0); STAGE_B(0, 1, 0);
    STAGE_B(1, 0, 1); STAGE_B(1, 1, 1);
    asm volatile("s_waitcnt vmcnt(4)" ::: "memory");
    __builtin_amdgcn_s_barrier();

    for (int kt = 0; kt < NT_K; kt += 2) {
        #pragma unroll
        for (int p = 0; p < 2; ++p) {
            const int cn  = p ^ 1;
            const int tn1 = (kt + p + 1) & (NT_K - 1);   // wrap staging at the end
            const int tn2 = (kt + p + 2) & (NT_K - 1);   // (hazard-safe, never read)

            bf16x8 aLo[4][2], aHi[4][2], bLo[2][2], bHi[2][2];

            // ---- phase 1: Q00 (aLo x bLo); 12 ds_reads kk0-first; stage A0(t+1) ----
            #pragma unroll
            for (int m = 0; m < 4; ++m) aLo[m][0] = LDA_F(p, m, 0);
            #pragma unroll
            for (int n = 0; n < 2; ++n) bLo[n][0] = LDB_F(p, n, 0);
            SB0();
            #pragma unroll
            for (int m = 0; m < 4; ++m) aLo[m][1] = LDA_F(p, m, 1);
            #pragma unroll
            for (int n = 0; n < 2; ++n) bLo[n][1] = LDB_F(p, n, 1);
            STAGE_A(cn, 0, tn1);
            __builtin_amdgcn_s_barrier();
            asm volatile("s_waitcnt lgkmcnt(6)" ::: "memory");
            SB0();
            __builtin_amdgcn_s_setprio(1);
            #pragma unroll
            for (int m = 0; m < 4; ++m)
                #pragma unroll
                for (int n = 0; n < 2; ++n)
                    acc[m][n] = __builtin_amdgcn_mfma_f32_16x16x32_bf16(aLo[m][0], bLo[n][0], acc[m][n], 0, 0, 0);
            SB0();
            asm volatile("s_waitcnt lgkmcnt(0)" ::: "memory");
            SB0();
            #pragma unroll
            for (int m = 0; m < 4; ++m)
                #pragma unroll
                for (int n = 0; n < 2; ++n)
                    acc[m][n] = __builtin_amdgcn_mfma_f32_16x16x32_bf16(aLo[m][1], bLo[n][1], acc[m][n], 0, 0, 0);
            __builtin_amdgcn_s_setprio(0);
            SB0();
            __builtin_amdgcn_s_barrier();

            // ---- phase 2: Q01 (aLo x bHi); 4 ds_reads; stage A1(t+1) ----
            #pragma unroll
            for (int n = 0; n < 2; ++n) bHi[n][0] = LDB_F(p, n + 2, 0);
            SB0();
            #pragma unroll
            for (int n = 0; n < 2; ++n) bHi[n][1] = LDB_F(p, n + 2, 1);
            STAGE_A(cn, 1, tn1);
            __builtin_amdgcn_s_barrier();
            asm volatile("s_waitcnt lgkmcnt(2)" ::: "memory");
            SB0();
            __builtin_amdgcn_s_setprio(1);
            #pragma unroll
            for (int m = 0; m < 4; ++m)
                #pragma unroll
                for (int n = 0; n < 2; ++n)
                    acc[m][n + 2] = __builtin_amdgcn_mfma_f32_16x16x32_bf16(aLo[m][0], bHi[n][0], acc[m][n + 2], 0, 0, 0);
            SB0();
            asm volatile("s_waitcnt lgkmcnt(0)" ::: "memory");
            SB0();
            #pragma unroll
            for (int m = 0; m < 4; ++m)
                #pragma unroll
                for (int n = 0; n < 2; ++n)
                    acc[m][n + 2] = __builtin_amdgcn_mfma_f32_16x16x32_bf16(aLo[m][1], bHi[n][1], acc[m][n + 2], 0, 0, 0);
            __builtin_amdgcn_s_setprio(0);
            SB0();
            __builtin_amdgcn_s_barrier();

            // ---- phase 3: Q11 (aHi x bHi); 8 ds_reads; stage B0(t+2) ----
            #pragma unroll
            for (int m = 0; m < 4; ++m) aHi[m][0] = LDA_F(p, m + 4, 0);
            SB0();
            #pragma unroll
            for (int m = 0; m < 4; ++m) aHi[m][1] = LDA_F(p, m + 4, 1);
            STAGE_B(p, 0, tn2);
            __builtin_amdgcn_s_barrier();
            asm volatile("s_waitcnt lgkmcnt(4)" ::: "memory");
            SB0();
            __builtin_amdgcn_s_setprio(1);
            #pragma unroll
            for (int m = 0; m < 4; ++m)
                #pragma unroll
                for (int n = 0; n < 2; ++n)
                    acc[m + 4][n + 2] = __builtin_amdgcn_mfma_f32_16x16x32_bf16(aHi[m][0], bHi[n][0], acc[m + 4][n + 2], 0, 0, 0);
            SB0();
            asm volatile("s_waitcnt lgkmcnt(0)" ::: "memory");
            SB0();
            #pragma unroll
            for (int m = 0; m < 4; ++m)
                #pragma unroll
                for (int n = 0; n < 2; ++n)
                    acc[m + 4][n + 2] = __builtin_amdgcn_mfma_f32_16x16x32_bf16(aHi[m][1], bHi[n][1], acc[m + 4][n + 2], 0, 0, 0);
            __builtin_amdgcn_s_setprio(0);
            SB0();
            __builtin_amdgcn_s_barrier();

            // ---- phase 4: Q10 (aHi x bLo); 0 ds_reads; stage B1(t+2); vmcnt(4) ----
            STAGE_B(p, 1, tn2);
            __builtin_amdgcn_s_barrier();
            __builtin_amdgcn_s_setprio(1);
            #pragma unroll
            for (int m = 0; m < 4; ++m)
                #pragma unroll
                for (int n = 0; n < 2; ++n)
                    acc[m + 4][n] = __builtin_amdgcn_mfma_f32_16x16x32_bf16(aHi[m][0], bLo[n][0], acc[m + 4][n], 0, 0, 0);
            #pragma unroll
            for (int m = 0; m < 4; ++m)
                #pragma unroll
                for (int n = 0; n < 2; ++n)
                    acc[m + 4][n] = __builtin_amdgcn_mfma_f32_16x16x32_bf16(aHi[m][1], bLo[n][1], acc[m + 4][n], 0, 0, 0);
            __builtin_amdgcn_s_setprio(0);
            SB0();
            asm volatile("s_waitcnt vmcnt(4)" ::: "memory");
            __builtin_amdgcn_s_barrier();
        }
    }

    asm volatile("s_waitcnt vmcnt(0)" ::: "memory");

    // epilogue: D col=lane&15, row=(lane>>4)*4+r
    const int crow = (lane >> 4) * 4;
    #pragma unroll
    for (int m = 0; m < 8; ++m)
        #pragma unroll
        for (int n = 0; n < 4; ++n)
            #pragma unroll
            for (int r = 0; r < 4; ++r)
                out[(size_t)(m0 + wm * 128 + m * 16 + crow + r) * N_OUT +
                    (o0 + wn * 64 + n * 16 + fr)] = acc[m][n][r];

#undef STAGE_A
#undef STAGE_B
#undef LDA_F
#undef LDB_F
#undef SB0
}

// ---------------- fallback: fused dequant GEMM (round-1 kernel) ----------------
__device__ __forceinline__ int fswz(int row, int byte_off) {
    return row * 128 + (byte_off ^ ((row & 7) << 4));
}

__global__ __launch_bounds__(256) void int4_gemm_fused(
    const float* __restrict__ x,
    const int*   __restrict__ wq,
    const float* __restrict__ sz,
    float*       __restrict__ out)
{
    __shared__ short A_lds[128 * 64];
    __shared__ short B_lds[128 * 64];
    char* Ab = (char*)A_lds;
    char* Bb = (char*)B_lds;

    const int bid = blockIdx.x;
    const int mt = bid / 32;
    const int nt = bid % 32;
    const int m0 = mt * 128;
    const int o0 = nt * 128;

    const int t    = threadIdx.x;
    const int lane = t & 63;
    const int wid  = t >> 6;
    const int wr   = wid >> 1;
    const int wc   = wid & 1;
    const int sr = t >> 4;
    const int sc = (t & 15) * 4;

    f32x4 acc[4][4];
    #pragma unroll
    for (int i = 0; i < 4; ++i)
        #pragma unroll
        for (int j = 0; j < 4; ++j)
            acc[i][j] = (f32x4){0.f, 0.f, 0.f, 0.f};

    const int frag_r = lane & 15;
    const int kb     = (lane >> 4) * 8;

    for (int kt = 0; kt < K_IN / 64; ++kt) {
        const int k0 = kt * 64;
        const int g  = k0 >> 7;
        #pragma unroll
        for (int it = 0; it < 8; ++it) {
            const int row = it * 16 + sr;
            const float4 v = *(const float4*)(x + (size_t)(m0 + row) * K_IN + k0 + sc);
            ushort4 h;
            h.x = f2bf(v.x); h.y = f2bf(v.y); h.z = f2bf(v.z); h.w = f2bf(v.w);
            *(ushort4*)(Ab + fswz(row, sc * 2)) = h;
        }
        #pragma unroll
        for (int it = 0; it < 8; ++it) {
            const int row = it * 16 + sr;
            const int4 q = *(const int4*)(wq + (size_t)(o0 + row) * K_IN + k0 + sc);
            const float2 s2 = *(const float2*)(sz + ((size_t)g * N_OUT + o0 + row) * 2);
            ushort4 h;
            h.x = f2bf((float)(q.x - 8) * s2.x + s2.y);
            h.y = f2bf((float)(q.y - 8) * s2.x + s2.y);
            h.z = f2bf((float)(q.z - 8) * s2.x + s2.y);
            h.w = f2bf((float)(q.w - 8) * s2.x + s2.y);
            *(ushort4*)(Bb + fswz(row, sc * 2)) = h;
        }
        __syncthreads();

        #pragma unroll
        for (int kk = 0; kk < 64; kk += 32) {
            bf16x8 a[4], b[4];
            #pragma unroll
            for (int i = 0; i < 4; ++i)
                a[i] = *(const bf16x8*)(Ab + fswz(wr * 64 + i * 16 + frag_r, (kk + kb) * 2));
            #pragma unroll
            for (int j = 0; j < 4; ++j)
                b[j] = *(const bf16x8*)(Bb + fswz(wc * 64 + j * 16 + frag_r, (kk + kb) * 2));
            #pragma unroll
            for (int i = 0; i < 4; ++i)
                #pragma unroll
                for (int j = 0; j < 4; ++j)
                    acc[i][j] = __builtin_amdgcn_mfma_f32_16x16x32_bf16(a[i], b[j], acc[i][j], 0, 0, 0);
        }
        __syncthreads();
    }

    const int crow = (lane >> 4) * 4;
    #pragma unroll
    for (int i = 0; i < 4; ++i)
        #pragma unroll
        for (int j = 0; j < 4; ++j)
            #pragma unroll
            for (int r = 0; r < 4; ++r) {
                const int gr = m0 + wr * 64 + i * 16 + crow + r;
                const int gc = o0 + wc * 64 + j * 16 + frag_r;
                out[(size_t)gr * N_OUT + gc] = acc[i][j][r];
            }
}

extern "C" void kernel_launch(void* const* d_in, const int* in_sizes, int n_in,
                              void* d_out, int out_size, void* d_ws, size_t ws_size,
                              hipStream_t stream) {
    const float* x  = (const float*)d_in[0];
    const int*   wq = (const int*)d_in[1];
    const float* sz = (const float*)d_in[2];
    float* out = (float*)d_out;

    const size_t need = ((size_t)M_ROWS * K_IN + (size_t)N_OUT * K_IN) * sizeof(unsigned short);
    if (ws_size >= need) {
        unsigned short* xb = (unsigned short*)d_ws;
        unsigned short* wb = xb + (size_t)M_ROWS * K_IN;
        hipLaunchKernelGGL(conv_all, dim3(3072), dim3(256), 0, stream, x, wq, sz, xb, wb);
        hipLaunchKernelGGL(gemm_8ph, dim3(NWG), dim3(512), 0, stream, xb, wb, out);
    } else {
        hipLaunchKernelGGL(int4_gemm_fused, dim3(2048), dim3(256), 0, stream, x, wq, sz, out);
    }
}

// Round 5
// 297.523 us; speedup vs baseline: 4.9525x; 1.0084x over previous
//
#include <hip/hip_runtime.h>
#include <hip/hip_bf16.h>
#include <stdint.h>

// WeightOnlyInt4Linear: C[M,N] = x[M,K] @ W^T, W = dequant int4 (group=128 on K).
// Step 1: fused memory-bound prepass converts x->bf16 and W->bf16 into d_ws.
// Step 2: 256x256 bf16 GEMM, 4-phase schedule with MINIMAL barriers (4/K-tile:
//         only load-bearing syncs kept), T2 swizzle + counted-vmcnt + setprio.

#define M_ROWS 8192
#define N_OUT  4096
#define K_IN   4096
#define NT_K   64           // K tiles of BK=64
#define NWG    512          // (8192/256) * (4096/256) = 32*16

typedef __attribute__((ext_vector_type(8))) short bf16x8;
typedef __attribute__((ext_vector_type(4))) float f32x4;

__device__ __forceinline__ unsigned short f2bf(float f) {
    union { float f; unsigned u; } c; c.f = f;
    return (unsigned short)((c.u + 0x7FFFu + ((c.u >> 16) & 1u)) >> 16);  // RNE
}

__device__ __forceinline__ void gload_lds16(const void* g, void* l) {
    __builtin_amdgcn_global_load_lds(
        (const __attribute__((address_space(1))) void*)g,
        (__attribute__((address_space(3))) void*)l, 16, 0, 0);
}

// ---------------- fused prepass: x f32->bf16 AND wq int4->bf16 ----------------
#define NXCH (M_ROWS * K_IN / 4)   // 8388608 float4 chunks
#define NWCH (N_OUT * K_IN / 4)    // 4194304 int4 chunks
__global__ __launch_bounds__(256) void conv_all(const float* __restrict__ x,
                                                const int*   __restrict__ wq,
                                                const float* __restrict__ sz,
                                                unsigned short* __restrict__ xb,
                                                unsigned short* __restrict__ wb) {
    const int stride = gridDim.x * blockDim.x;
    for (int c = blockIdx.x * blockDim.x + threadIdx.x; c < NXCH + NWCH; c += stride) {
        if (c < NXCH) {
            const float4 v = ((const float4*)x)[c];
            ushort4 h;
            h.x = f2bf(v.x); h.y = f2bf(v.y); h.z = f2bf(v.z); h.w = f2bf(v.w);
            ((ushort4*)xb)[c] = h;
        } else {
            const int cw = c - NXCH;
            const int4 q = ((const int4*)wq)[cw];
            const int o  = cw >> 10;            // K/4 = 1024 chunks per out-row
            const int g  = (cw & 1023) >> 5;    // *4/128
            const float2 s2 = *(const float2*)(sz + ((size_t)g * N_OUT + o) * 2);
            ushort4 h;
            h.x = f2bf((float)(q.x - 8) * s2.x + s2.y);
            h.y = f2bf((float)(q.y - 8) * s2.x + s2.y);
            h.z = f2bf((float)(q.z - 8) * s2.x + s2.y);
            h.w = f2bf((float)(q.w - 8) * s2.x + s2.y);
            ((ushort4*)wb)[cw] = h;
        }
    }
}

// ---------------- main GEMM: 256^2, minimal-barrier 4-phase ----------------
// A = xb [M,K] bf16 row-major; B = wb [N,K] bf16 row-major; C fp32 [M,N].
__global__ __launch_bounds__(512) void gemm_8ph(const unsigned short* __restrict__ A,
                                                const unsigned short* __restrict__ B,
                                                float* __restrict__ out) {
    __shared__ short Als[2 * 256 * 64];   // 64 KiB: 2 dbuf x [256 rows][64 bf16]
    __shared__ short Bls[2 * 256 * 64];   // 64 KiB

    const int bid = blockIdx.x;
    const int swb = (bid & 7) * (NWG / 8) + (bid >> 3);   // bijective XCD swizzle
    const int m0 = (swb >> 4) * 256;
    const int o0 = (swb & 15) * 256;

    const int t    = threadIdx.x;
    const int lane = t & 63;
    const int wid  = t >> 6;
    const int wm   = wid >> 2;   // 0..1 -> 128-row half of A
    const int wn   = wid & 3;    // 0..3 -> 64-row stripe of B

    // staging: LDS dest linear; global source col pre-swizzled (same XOR involution)
    const int srow = lane >> 3;                    // 0..7 row within 1KiB chunk
    const int scol = ((lane & 7) ^ srow) * 8;      // pre-swizzled element col
    // fragment-read geometry
    const int fr   = lane & 15;
    const int rxm  = (fr & 7) << 4;                // XOR mask (row&7)<<4
    const int cb0  = (lane >> 4) * 16;             // col byte base within k-step

#define STAGE_A(BUF, H, ST) do { \
    const int k0_ = (ST) * 64; \
    _Pragma("unroll") \
    for (int l_ = 0; l_ < 2; ++l_) { \
        const int ch_ = wid * 2 + l_; \
        const int row_ = (H) * 128 + ch_ * 8 + srow; \
        gload_lds16(A + (size_t)(m0 + row_) * K_IN + k0_ + scol, \
                    (char*)Als + (BUF) * 32768 + (H) * 16384 + ch_ * 1024); \
    } } while (0)

#define STAGE_B(BUF, H, ST) do { \
    const int k0_ = (ST) * 64; \
    _Pragma("unroll") \
    for (int l_ = 0; l_ < 2; ++l_) { \
        const int ch_ = wid * 2 + l_; \
        const int row_ = (H) * 128 + ch_ * 8 + srow; \
        gload_lds16(B + (size_t)(o0 + row_) * K_IN + k0_ + scol, \
                    (char*)Bls + (BUF) * 32768 + (H) * 16384 + ch_ * 1024); \
    } } while (0)

#define LDA_F(BUF, M, KK) (*(const bf16x8*)((const char*)Als + (BUF) * 32768 + \
    (wm * 128 + (M) * 16 + fr) * 128 + ((((KK) * 64) + cb0) ^ rxm)))
#define LDB_F(BUF, N, KK) (*(const bf16x8*)((const char*)Bls + (BUF) * 32768 + \
    (wn * 64 + (N) * 16 + fr) * 128 + ((((KK) * 64) + cb0) ^ rxm)))

#define SB0() __builtin_amdgcn_sched_barrier(0)

    f32x4 acc[8][4];
    #pragma unroll
    for (int m = 0; m < 8; ++m)
        #pragma unroll
        for (int n = 0; n < 4; ++n)
            acc[m][n] = (f32x4){0.f, 0.f, 0.f, 0.f};

    // prologue: tile0 {A0,A1,B0,B1} + tile1 {B0,B1}; wait tile0 (4 loads in flight)
    STAGE_A(0, 0, 0); STAGE_A(0, 1, 0); STAGE_B(0, 0, 0); STAGE_B(0, 1, 0);
    STAGE_B(1, 0, 1); STAGE_B(1, 1, 1);
    asm volatile("s_waitcnt vmcnt(4)" ::: "memory");
    __builtin_amdgcn_s_barrier();

    for (int kt = 0; kt < NT_K; kt += 2) {
        #pragma unroll
        for (int p = 0; p < 2; ++p) {
            const int cn  = p ^ 1;
            const int tn1 = (kt + p + 1) & (NT_K - 1);   // wrap staging at the end
            const int tn2 = (kt + p + 2) & (NT_K - 1);   // (hazard-safe, never read)

            bf16x8 aLo[4][2], aHi[4][2], bLo[2][2], bHi[2][2];

            // ---- P1: reads aLo+bLo (12); stage A0(t+1); BAR; Q00 ----
            #pragma unroll
            for (int m = 0; m < 4; ++m) { aLo[m][0] = LDA_F(p, m, 0); aLo[m][1] = LDA_F(p, m, 1); }
            #pragma unroll
            for (int n = 0; n < 2; ++n) { bLo[n][0] = LDB_F(p, n, 0); bLo[n][1] = LDB_F(p, n, 1); }
            STAGE_A(cn, 0, tn1);
            SB0();
            __builtin_amdgcn_s_barrier();
            asm volatile("s_waitcnt lgkmcnt(0)" ::: "memory");
            SB0();
            __builtin_amdgcn_s_setprio(1);
            #pragma unroll
            for (int m = 0; m < 4; ++m)
                #pragma unroll
                for (int n = 0; n < 2; ++n) {
                    acc[m][n] = __builtin_amdgcn_mfma_f32_16x16x32_bf16(aLo[m][0], bLo[n][0], acc[m][n], 0, 0, 0);
                    acc[m][n] = __builtin_amdgcn_mfma_f32_16x16x32_bf16(aLo[m][1], bLo[n][1], acc[m][n], 0, 0, 0);
                }
            __builtin_amdgcn_s_setprio(0);
            SB0();
            // (no closing barrier: next phase reads same buffer, no hazard)

            // ---- P2: reads bHi (4); stage A1(t+1); BAR; Q01 ----
            #pragma unroll
            for (int n = 0; n < 2; ++n) { bHi[n][0] = LDB_F(p, n + 2, 0); bHi[n][1] = LDB_F(p, n + 2, 1); }
            STAGE_A(cn, 1, tn1);
            SB0();
            __builtin_amdgcn_s_barrier();
            asm volatile("s_waitcnt lgkmcnt(0)" ::: "memory");
            SB0();
            __builtin_amdgcn_s_setprio(1);
            #pragma unroll
            for (int m = 0; m < 4; ++m)
                #pragma unroll
                for (int n = 0; n < 2; ++n) {
                    acc[m][n + 2] = __builtin_amdgcn_mfma_f32_16x16x32_bf16(aLo[m][0], bHi[n][0], acc[m][n + 2], 0, 0, 0);
                    acc[m][n + 2] = __builtin_amdgcn_mfma_f32_16x16x32_bf16(aLo[m][1], bHi[n][1], acc[m][n + 2], 0, 0, 0);
                }
            __builtin_amdgcn_s_setprio(0);
            SB0();

            // ---- P3: reads aHi (8); BAR (last B-read drained by all waves);
            //          THEN stage B0(t+2) into buffer p; Q11 ----
            #pragma unroll
            for (int m = 0; m < 4; ++m) { aHi[m][0] = LDA_F(p, m + 4, 0); aHi[m][1] = LDA_F(p, m + 4, 1); }
            SB0();
            __builtin_amdgcn_s_barrier();
            SB0();
            STAGE_B(p, 0, tn2);
            asm volatile("s_waitcnt lgkmcnt(0)" ::: "memory");
            SB0();
            __builtin_amdgcn_s_setprio(1);
            #pragma unroll
            for (int m = 0; m < 4; ++m)
                #pragma unroll
                for (int n = 0; n < 2; ++n) {
                    acc[m + 4][n + 2] = __builtin_amdgcn_mfma_f32_16x16x32_bf16(aHi[m][0], bHi[n][0], acc[m + 4][n + 2], 0, 0, 0);
                    acc[m + 4][n + 2] = __builtin_amdgcn_mfma_f32_16x16x32_bf16(aHi[m][1], bHi[n][1], acc[m + 4][n + 2], 0, 0, 0);
                }
            __builtin_amdgcn_s_setprio(0);
            SB0();

            // ---- P4 (merged): stage B1(t+2); Q10; counted vmcnt; boundary BAR ----
            STAGE_B(p, 1, tn2);
            __builtin_amdgcn_s_setprio(1);
            #pragma unroll
            for (int m = 0; m < 4; ++m)
                #pragma unroll
                for (int n = 0; n < 2; ++n) {
                    acc[m + 4][n] = __builtin_amdgcn_mfma_f32_16x16x32_bf16(aHi[m][0], bLo[n][0], acc[m + 4][n], 0, 0, 0);
                    acc[m + 4][n] = __builtin_amdgcn_mfma_f32_16x16x32_bf16(aHi[m][1], bLo[n][1], acc[m + 4][n], 0, 0, 0);
                }
            __builtin_amdgcn_s_setprio(0);
            SB0();
            asm volatile("s_waitcnt vmcnt(4)" ::: "memory");
            SB0();
            __builtin_amdgcn_s_barrier();
        }
    }

    asm volatile("s_waitcnt vmcnt(0)" ::: "memory");

    // epilogue: D col=lane&15, row=(lane>>4)*4+r
    const int crow = (lane >> 4) * 4;
    #pragma unroll
    for (int m = 0; m < 8; ++m)
        #pragma unroll
        for (int n = 0; n < 4; ++n)
            #pragma unroll
            for (int r = 0; r < 4; ++r)
                out[(size_t)(m0 + wm * 128 + m * 16 + crow + r) * N_OUT +
                    (o0 + wn * 64 + n * 16 + fr)] = acc[m][n][r];

#undef STAGE_A
#undef STAGE_B
#undef LDA_F
#undef LDB_F
#undef SB0
}

// ---------------- fallback: fused dequant GEMM (round-1 kernel) ----------------
__device__ __forceinline__ int fswz(int row, int byte_off) {
    return row * 128 + (byte_off ^ ((row & 7) << 4));
}

__global__ __launch_bounds__(256) void int4_gemm_fused(
    const float* __restrict__ x,
    const int*   __restrict__ wq,
    const float* __restrict__ sz,
    float*       __restrict__ out)
{
    __shared__ short A_lds[128 * 64];
    __shared__ short B_lds[128 * 64];
    char* Ab = (char*)A_lds;
    char* Bb = (char*)B_lds;

    const int bid = blockIdx.x;
    const int mt = bid / 32;
    const int nt = bid % 32;
    const int m0 = mt * 128;
    const int o0 = nt * 128;

    const int t    = threadIdx.x;
    const int lane = t & 63;
    const int wid  = t >> 6;
    const int wr   = wid >> 1;
    const int wc   = wid & 1;
    const int sr = t >> 4;
    const int sc = (t & 15) * 4;

    f32x4 acc[4][4];
    #pragma unroll
    for (int i = 0; i < 4; ++i)
        #pragma unroll
        for (int j = 0; j < 4; ++j)
            acc[i][j] = (f32x4){0.f, 0.f, 0.f, 0.f};

    const int frag_r = lane & 15;
    const int kb     = (lane >> 4) * 8;

    for (int kt = 0; kt < K_IN / 64; ++kt) {
        const int k0 = kt * 64;
        const int g  = k0 >> 7;
        #pragma unroll
        for (int it = 0; it < 8; ++it) {
            const int row = it * 16 + sr;
            const float4 v = *(const float4*)(x + (size_t)(m0 + row) * K_IN + k0 + sc);
            ushort4 h;
            h.x = f2bf(v.x); h.y = f2bf(v.y); h.z = f2bf(v.z); h.w = f2bf(v.w);
            *(ushort4*)(Ab + fswz(row, sc * 2)) = h;
        }
        #pragma unroll
        for (int it = 0; it < 8; ++it) {
            const int row = it * 16 + sr;
            const int4 q = *(const int4*)(wq + (size_t)(o0 + row) * K_IN + k0 + sc);
            const float2 s2 = *(const float2*)(sz + ((size_t)g * N_OUT + o0 + row) * 2);
            ushort4 h;
            h.x = f2bf((float)(q.x - 8) * s2.x + s2.y);
            h.y = f2bf((float)(q.y - 8) * s2.x + s2.y);
            h.z = f2bf((float)(q.z - 8) * s2.x + s2.y);
            h.w = f2bf((float)(q.w - 8) * s2.x + s2.y);
            *(ushort4*)(Bb + fswz(row, sc * 2)) = h;
        }
        __syncthreads();

        #pragma unroll
        for (int kk = 0; kk < 64; kk += 32) {
            bf16x8 a[4], b[4];
            #pragma unroll
            for (int i = 0; i < 4; ++i)
                a[i] = *(const bf16x8*)(Ab + fswz(wr * 64 + i * 16 + frag_r, (kk + kb) * 2));
            #pragma unroll
            for (int j = 0; j < 4; ++j)
                b[j] = *(const bf16x8*)(Bb + fswz(wc * 64 + j * 16 + frag_r, (kk + kb) * 2));
            #pragma unroll
            for (int i = 0; i < 4; ++i)
                #pragma unroll
                for (int j = 0; j < 4; ++j)
                    acc[i][j] = __builtin_amdgcn_mfma_f32_16x16x32_bf16(a[i], b[j], acc[i][j], 0, 0, 0);
        }
        __syncthreads();
    }

    const int crow = (lane >> 4) * 4;
    #pragma unroll
    for (int i = 0; i < 4; ++i)
        #pragma unroll
        for (int j = 0; j < 4; ++j)
            #pragma unroll
            for (int r = 0; r < 4; ++r) {
                const int gr = m0 + wr * 64 + i * 16 + crow + r;
                const int gc = o0 + wc * 64 + j * 16 + frag_r;
                out[(size_t)gr * N_OUT + gc] = acc[i][j][r];
            }
}

extern "C" void kernel_launch(void* const* d_in, const int* in_sizes, int n_in,
                              void* d_out, int out_size, void* d_ws, size_t ws_size,
                              hipStream_t stream) {
    const float* x  = (const float*)d_in[0];
    const int*   wq = (const int*)d_in[1];
    const float* sz = (const float*)d_in[2];
    float* out = (float*)d_out;

    const size_t need = ((size_t)M_ROWS * K_IN + (size_t)N_OUT * K_IN) * sizeof(unsigned short);
    if (ws_size >= need) {
        unsigned short* xb = (unsigned short*)d_ws;
        unsigned short* wb = xb + (size_t)M_ROWS * K_IN;
        hipLaunchKernelGGL(conv_all, dim3(3072), dim3(256), 0, stream, x, wq, sz, xb, wb);
        hipLaunchKernelGGL(gemm_8ph, dim3(NWG), dim3(512), 0, stream, xb, wb, out);
    } else {
        hipLaunchKernelGGL(int4_gemm_fused, dim3(2048), dim3(256), 0, stream, x, wq, sz, out);
    }
}

// Round 6
// 276.664 us; speedup vs baseline: 5.3259x; 1.0754x over previous
//
#include <hip/hip_runtime.h>
#include <hip/hip_bf16.h>
#include <stdint.h>

// WeightOnlyInt4Linear: C[M,N] = x[M,K] @ W^T, W = dequant int4 (group=128 on K).
// Step 1: fused memory-bound prepass converts x->bf16 and W->bf16 into d_ws.
// Step 2: 256x256 bf16 GEMM, ONE barrier per K-tile: A double-buffered,
//         B TRIPLE-buffered (stage distance 2 never hits read buffer),
//         counted lgkmcnt gates per-quadrant MFMA (reads overlap MFMA),
//         counted vmcnt(4) at tile boundary, T2 swizzle, setprio.

#define M_ROWS 8192
#define N_OUT  4096
#define K_IN   4096
#define NT_K   64           // K tiles of BK=64
#define NWG    512          // (8192/256) * (4096/256) = 32*16

typedef __attribute__((ext_vector_type(8))) short bf16x8;
typedef __attribute__((ext_vector_type(4))) float f32x4;

__device__ __forceinline__ unsigned short f2bf(float f) {
    union { float f; unsigned u; } c; c.f = f;
    return (unsigned short)((c.u + 0x7FFFu + ((c.u >> 16) & 1u)) >> 16);  // RNE
}

__device__ __forceinline__ void gload_lds16(const void* g, void* l) {
    __builtin_amdgcn_global_load_lds(
        (const __attribute__((address_space(1))) void*)g,
        (__attribute__((address_space(3))) void*)l, 16, 0, 0);
}

// ---------------- fused prepass: x f32->bf16 AND wq int4->bf16 ----------------
#define NXCH (M_ROWS * K_IN / 4)   // 8388608 float4 chunks
#define NWCH (N_OUT * K_IN / 4)    // 4194304 int4 chunks
__global__ __launch_bounds__(256) void conv_all(const float* __restrict__ x,
                                                const int*   __restrict__ wq,
                                                const float* __restrict__ sz,
                                                unsigned short* __restrict__ xb,
                                                unsigned short* __restrict__ wb) {
    const int stride = gridDim.x * blockDim.x;
    for (int c = blockIdx.x * blockDim.x + threadIdx.x; c < NXCH + NWCH; c += stride) {
        if (c < NXCH) {
            const float4 v = ((const float4*)x)[c];
            ushort4 h;
            h.x = f2bf(v.x); h.y = f2bf(v.y); h.z = f2bf(v.z); h.w = f2bf(v.w);
            ((ushort4*)xb)[c] = h;
        } else {
            const int cw = c - NXCH;
            const int4 q = ((const int4*)wq)[cw];
            const int o  = cw >> 10;            // K/4 = 1024 chunks per out-row
            const int g  = (cw & 1023) >> 5;    // *4/128
            const float2 s2 = *(const float2*)(sz + ((size_t)g * N_OUT + o) * 2);
            ushort4 h;
            h.x = f2bf((float)(q.x - 8) * s2.x + s2.y);
            h.y = f2bf((float)(q.y - 8) * s2.x + s2.y);
            h.z = f2bf((float)(q.z - 8) * s2.x + s2.y);
            h.w = f2bf((float)(q.w - 8) * s2.x + s2.y);
            ((ushort4*)wb)[cw] = h;
        }
    }
}

// ---------------- main GEMM: 256^2, 1 barrier/K-tile, tri-buffered B ----------------
// A = xb [M,K] bf16 row-major; B = wb [N,K] bf16 row-major; C fp32 [M,N].
__global__ __launch_bounds__(512) void gemm_1b(const unsigned short* __restrict__ A,
                                               const unsigned short* __restrict__ B,
                                               float* __restrict__ out) {
    __shared__ short Als[2 * 256 * 64];   // 64 KiB: A dbuf
    __shared__ short Bls[3 * 256 * 64];   // 96 KiB: B tri-buf (stage dist 2, mod 3)

    const int bid = blockIdx.x;
    const int swb = (bid & 7) * (NWG / 8) + (bid >> 3);   // bijective XCD swizzle
    const int m0 = (swb >> 4) * 256;
    const int o0 = (swb & 15) * 256;

    const int t    = threadIdx.x;
    const int lane = t & 63;
    const int wid  = t >> 6;
    const int wm   = wid >> 2;   // 0..1 -> 128-row half of A
    const int wn   = wid & 3;    // 0..3 -> 64-row stripe of B

    // staging: LDS dest linear (base+lane*16); global source col pre-swizzled
    const int srow = lane >> 3;                    // 0..7 row within 1KiB chunk
    const int scol = ((lane & 7) ^ srow) * 8;      // pre-swizzled element col
    // fragment-read geometry
    const int fr   = lane & 15;
    const int rxm  = (fr & 7) << 4;                // XOR mask (row&7)<<4
    const int cb0  = (lane >> 4) * 16;             // col byte base within k-step

    const unsigned short* Ag = A + (size_t)m0 * K_IN;
    const unsigned short* Bg = B + (size_t)o0 * K_IN;

// stage one 128-row half (32 KB/2 halves -> 16 KB) of a K-tile into LBASE
#define STAGE_HALF(GB, R0, KT, LB) do { \
    const int k0_ = (KT) * 64; \
    _Pragma("unroll") \
    for (int l_ = 0; l_ < 2; ++l_) { \
        const int ch_ = wid * 2 + l_; \
        const int row_ = (R0) + ch_ * 8 + srow; \
        gload_lds16(GB + (size_t)row_ * K_IN + k0_ + scol, (char*)(LB) + ch_ * 1024); \
    } } while (0)

#define LDA_F(BASE, M, KK) (*(const bf16x8*)((BASE) + \
    (wm * 128 + (M) * 16 + fr) * 128 + ((((KK) * 64) + cb0) ^ rxm)))
#define LDB_F(BASE, N, KK) (*(const bf16x8*)((BASE) + \
    (wn * 64 + (N) * 16 + fr) * 128 + ((((KK) * 64) + cb0) ^ rxm)))

#define SB0() __builtin_amdgcn_sched_barrier(0)

    f32x4 acc[8][4];
    #pragma unroll
    for (int m = 0; m < 8; ++m)
        #pragma unroll
        for (int n = 0; n < 4; ++n)
            acc[m][n] = (f32x4){0.f, 0.f, 0.f, 0.f};

    // prologue: tile0 A+B, tile1 B; wait tile0 (B(1)'s 4 loads stay in flight)
    STAGE_HALF(Ag, 0, 0, (char*)Als);
    STAGE_HALF(Ag, 128, 0, (char*)Als + 16384);
    STAGE_HALF(Bg, 0, 0, (char*)Bls);
    STAGE_HALF(Bg, 128, 0, (char*)Bls + 16384);
    STAGE_HALF(Bg, 0, 1, (char*)Bls + 32768);
    STAGE_HALF(Bg, 128, 1, (char*)Bls + 32768 + 16384);
    asm volatile("s_waitcnt vmcnt(4)" ::: "memory");
    __builtin_amdgcn_s_barrier();

    int bB = 0, bB2 = 2;   // B read buf = kt%3, B stage buf = (kt+2)%3
    #pragma unroll 1
    for (int kt = 0; kt < NT_K; ++kt) {
        const char* Ar = (char*)Als + ((kt & 1) << 15);
        const char* Br = (char*)Bls + (bB << 15);
        char* Aw = (char*)Als + (((kt + 1) & 1) << 15);
        char* Bw = (char*)Bls + (bB2 << 15);
        const int tn1 = (kt + 1) & (NT_K - 1);   // wrap staging at the end
        const int tn2 = (kt + 2) & (NT_K - 1);   // (hazard-safe, never read)

        bf16x8 aLo[4][2], aHi[4][2], bLo[2][2], bHi[2][2];

        // ---- issue all reads in counted groups: [aLo+bLo 12][bHi 4][aHi 8] ----
        #pragma unroll
        for (int m = 0; m < 4; ++m) { aLo[m][0] = LDA_F(Ar, m, 0); aLo[m][1] = LDA_F(Ar, m, 1); }
        #pragma unroll
        for (int n = 0; n < 2; ++n) { bLo[n][0] = LDB_F(Br, n, 0); bLo[n][1] = LDB_F(Br, n, 1); }
        SB0();
        #pragma unroll
        for (int n = 0; n < 2; ++n) { bHi[n][0] = LDB_F(Br, n + 2, 0); bHi[n][1] = LDB_F(Br, n + 2, 1); }
        SB0();
        #pragma unroll
        for (int m = 0; m < 4; ++m) { aHi[m][0] = LDA_F(Ar, m + 4, 0); aHi[m][1] = LDA_F(Ar, m + 4, 1); }
        SB0();

        // ---- issue staging: A(t+1) -> other A buf; B(t+2) -> tri-buf (never read buf) ----
        STAGE_HALF(Ag, 0, tn1, Aw);
        STAGE_HALF(Ag, 128, tn1, Aw + 16384);
        STAGE_HALF(Bg, 0, tn2, Bw);
        STAGE_HALF(Bg, 128, tn2, Bw + 16384);
        SB0();

        // ---- Q00: needs first 12 reads ----
        asm volatile("s_waitcnt lgkmcnt(12)" ::: "memory");
        SB0();
        __builtin_amdgcn_s_setprio(1);
        #pragma unroll
        for (int kk = 0; kk < 2; ++kk)
            #pragma unroll
            for (int m = 0; m < 4; ++m)
                #pragma unroll
                for (int n = 0; n < 2; ++n)
                    acc[m][n] = __builtin_amdgcn_mfma_f32_16x16x32_bf16(aLo[m][kk], bLo[n][kk], acc[m][n], 0, 0, 0);
        __builtin_amdgcn_s_setprio(0);
        SB0();

        // ---- Q01: needs bHi (first 16) ----
        asm volatile("s_waitcnt lgkmcnt(8)" ::: "memory");
        SB0();
        __builtin_amdgcn_s_setprio(1);
        #pragma unroll
        for (int kk = 0; kk < 2; ++kk)
            #pragma unroll
            for (int m = 0; m < 4; ++m)
                #pragma unroll
                for (int n = 0; n < 2; ++n)
                    acc[m][n + 2] = __builtin_amdgcn_mfma_f32_16x16x32_bf16(aLo[m][kk], bHi[n][kk], acc[m][n + 2], 0, 0, 0);
        __builtin_amdgcn_s_setprio(0);
        SB0();

        // ---- Q11 + Q10: needs all reads ----
        asm volatile("s_waitcnt lgkmcnt(0)" ::: "memory");
        SB0();
        __builtin_amdgcn_s_setprio(1);
        #pragma unroll
        for (int kk = 0; kk < 2; ++kk)
            #pragma unroll
            for (int m = 0; m < 4; ++m)
                #pragma unroll
                for (int n = 0; n < 2; ++n)
                    acc[m + 4][n + 2] = __builtin_amdgcn_mfma_f32_16x16x32_bf16(aHi[m][kk], bHi[n][kk], acc[m + 4][n + 2], 0, 0, 0);
        #pragma unroll
        for (int kk = 0; kk < 2; ++kk)
            #pragma unroll
            for (int m = 0; m < 4; ++m)
                #pragma unroll
                for (int n = 0; n < 2; ++n)
                    acc[m + 4][n] = __builtin_amdgcn_mfma_f32_16x16x32_bf16(aHi[m][kk], bLo[n][kk], acc[m + 4][n], 0, 0, 0);
        __builtin_amdgcn_s_setprio(0);
        SB0();

        // ---- tile boundary: publish A(t+1), B(t+1); keep B(t+2) in flight ----
        asm volatile("s_waitcnt vmcnt(4)" ::: "memory");
        SB0();
        __builtin_amdgcn_s_barrier();

        bB  = (bB  == 2) ? 0 : bB + 1;
        bB2 = (bB2 == 2) ? 0 : bB2 + 1;
    }

    asm volatile("s_waitcnt vmcnt(0)" ::: "memory");

    // epilogue: D col=lane&15, row=(lane>>4)*4+r
    const int crow = (lane >> 4) * 4;
    #pragma unroll
    for (int m = 0; m < 8; ++m)
        #pragma unroll
        for (int n = 0; n < 4; ++n)
            #pragma unroll
            for (int r = 0; r < 4; ++r)
                out[(size_t)(m0 + wm * 128 + m * 16 + crow + r) * N_OUT +
                    (o0 + wn * 64 + n * 16 + fr)] = acc[m][n][r];

#undef STAGE_HALF
#undef LDA_F
#undef LDB_F
#undef SB0
}

// ---------------- fallback: fused dequant GEMM (round-1 kernel) ----------------
__device__ __forceinline__ int fswz(int row, int byte_off) {
    return row * 128 + (byte_off ^ ((row & 7) << 4));
}

__global__ __launch_bounds__(256) void int4_gemm_fused(
    const float* __restrict__ x,
    const int*   __restrict__ wq,
    const float* __restrict__ sz,
    float*       __restrict__ out)
{
    __shared__ short A_lds[128 * 64];
    __shared__ short B_lds[128 * 64];
    char* Ab = (char*)A_lds;
    char* Bb = (char*)B_lds;

    const int bid = blockIdx.x;
    const int mt = bid / 32;
    const int nt = bid % 32;
    const int m0 = mt * 128;
    const int o0 = nt * 128;

    const int t    = threadIdx.x;
    const int lane = t & 63;
    const int wid  = t >> 6;
    const int wr   = wid >> 1;
    const int wc   = wid & 1;
    const int sr = t >> 4;
    const int sc = (t & 15) * 4;

    f32x4 acc[4][4];
    #pragma unroll
    for (int i = 0; i < 4; ++i)
        #pragma unroll
        for (int j = 0; j < 4; ++j)
            acc[i][j] = (f32x4){0.f, 0.f, 0.f, 0.f};

    const int frag_r = lane & 15;
    const int kb     = (lane >> 4) * 8;

    for (int kt = 0; kt < K_IN / 64; ++kt) {
        const int k0 = kt * 64;
        const int g  = k0 >> 7;
        #pragma unroll
        for (int it = 0; it < 8; ++it) {
            const int row = it * 16 + sr;
            const float4 v = *(const float4*)(x + (size_t)(m0 + row) * K_IN + k0 + sc);
            ushort4 h;
            h.x = f2bf(v.x); h.y = f2bf(v.y); h.z = f2bf(v.z); h.w = f2bf(v.w);
            *(ushort4*)(Ab + fswz(row, sc * 2)) = h;
        }
        #pragma unroll
        for (int it = 0; it < 8; ++it) {
            const int row = it * 16 + sr;
            const int4 q = *(const int4*)(wq + (size_t)(o0 + row) * K_IN + k0 + sc);
            const float2 s2 = *(const float2*)(sz + ((size_t)g * N_OUT + o0 + row) * 2);
            ushort4 h;
            h.x = f2bf((float)(q.x - 8) * s2.x + s2.y);
            h.y = f2bf((float)(q.y - 8) * s2.x + s2.y);
            h.z = f2bf((float)(q.z - 8) * s2.x + s2.y);
            h.w = f2bf((float)(q.w - 8) * s2.x + s2.y);
            *(ushort4*)(Bb + fswz(row, sc * 2)) = h;
        }
        __syncthreads();

        #pragma unroll
        for (int kk = 0; kk < 64; kk += 32) {
            bf16x8 a[4], b[4];
            #pragma unroll
            for (int i = 0; i < 4; ++i)
                a[i] = *(const bf16x8*)(Ab + fswz(wr * 64 + i * 16 + frag_r, (kk + kb) * 2));
            #pragma unroll
            for (int j = 0; j < 4; ++j)
                b[j] = *(const bf16x8*)(Bb + fswz(wc * 64 + j * 16 + frag_r, (kk + kb) * 2));
            #pragma unroll
            for (int i = 0; i < 4; ++i)
                #pragma unroll
                for (int j = 0; j < 4; ++j)
                    acc[i][j] = __builtin_amdgcn_mfma_f32_16x16x32_bf16(a[i], b[j], acc[i][j], 0, 0, 0);
        }
        __syncthreads();
    }

    const int crow = (lane >> 4) * 4;
    #pragma unroll
    for (int i = 0; i < 4; ++i)
        #pragma unroll
        for (int j = 0; j < 4; ++j)
            #pragma unroll
            for (int r = 0; r < 4; ++r) {
                const int gr = m0 + wr * 64 + i * 16 + crow + r;
                const int gc = o0 + wc * 64 + j * 16 + frag_r;
                out[(size_t)gr * N_OUT + gc] = acc[i][j][r];
            }
}

extern "C" void kernel_launch(void* const* d_in, const int* in_sizes, int n_in,
                              void* d_out, int out_size, void* d_ws, size_t ws_size,
                              hipStream_t stream) {
    const float* x  = (const float*)d_in[0];
    const int*   wq = (const int*)d_in[1];
    const float* sz = (const float*)d_in[2];
    float* out = (float*)d_out;

    const size_t need = ((size_t)M_ROWS * K_IN + (size_t)N_OUT * K_IN) * sizeof(unsigned short);
    if (ws_size >= need) {
        unsigned short* xb = (unsigned short*)d_ws;
        unsigned short* wb = xb + (size_t)M_ROWS * K_IN;
        hipLaunchKernelGGL(conv_all, dim3(3072), dim3(256), 0, stream, x, wq, sz, xb, wb);
        hipLaunchKernelGGL(gemm_1b, dim3(NWG), dim3(512), 0, stream, xb, wb, out);
    } else {
        hipLaunchKernelGGL(int4_gemm_fused, dim3(2048), dim3(256), 0, stream, x, wq, sz, out);
    }
}